// Round 1
// baseline (51.227 us; speedup 1.0000x reference)
//
#include <hip/hip_runtime.h>
#include <math.h>

// L = diag((W+W^T).sum(1)) - (W+W^T), W scattered from per-face cotangent weights.
// For each face corner scatter (r, c, v):
//   L[r][c] -= v ; L[c][r] -= v ; L[r][r] += v ; L[c][c] += v
// (matches reference including the r==c degenerate case, which nets to zero)

__global__ void face_scatter_kernel(const float* __restrict__ V,
                                    const int* __restrict__ Fw,
                                    float* __restrict__ L,
                                    int nF, int N) {
    int f = blockIdx.x * blockDim.x + threadIdx.x;
    if (f >= nF) return;

    // Detect whether F was shipped as int64 (little-endian: odd words are the
    // all-zero high halves) or int32. Values are in [0, 8192) so genuine int32
    // data has ~(1/8192)^6 chance of tripping this — negligible & deterministic.
    const bool is64 = (Fw[1] == 0) && (Fw[3] == 0) && (Fw[5] == 0) &&
                      (Fw[7] == 0) && (Fw[9] == 0) && (Fw[11] == 0);

    int i0, i1, i2;
    if (is64) {
        const int base = f * 6;
        i0 = Fw[base + 0];
        i1 = Fw[base + 2];
        i2 = Fw[base + 4];
    } else {
        const int base = f * 3;
        i0 = Fw[base + 0];
        i1 = Fw[base + 1];
        i2 = Fw[base + 2];
    }

    // v1 = V[F0], v2 = V[F1], v3 = V[F2]
    const float ax = V[i0 * 3 + 0], ay = V[i0 * 3 + 1], az = V[i0 * 3 + 2];
    const float bx = V[i1 * 3 + 0], by = V[i1 * 3 + 1], bz = V[i1 * 3 + 2];
    const float cx = V[i2 * 3 + 0], cy = V[i2 * 3 + 1], cz = V[i2 * 3 + 2];

    // safe norms: l1=|v2-v3|, l2=|v3-v1|, l3=|v1-v2|
    float dx, dy, dz, d2;
    dx = bx - cx; dy = by - cy; dz = bz - cz;
    d2 = dx * dx + dy * dy + dz * dz;
    const float l1 = (d2 > 0.0f) ? sqrtf(d2) : 0.0f;
    dx = cx - ax; dy = cy - ay; dz = cz - az;
    d2 = dx * dx + dy * dy + dz * dz;
    const float l2 = (d2 > 0.0f) ? sqrtf(d2) : 0.0f;
    dx = ax - bx; dy = ay - by; dz = az - bz;
    d2 = dx * dx + dy * dy + dz * dz;
    const float l3 = (d2 > 0.0f) ? sqrtf(d2) : 0.0f;

    const float sp = (l1 + l2 + l3) * 0.5f;
    const float s  = sp * (sp - l1) * (sp - l2) * (sp - l3);
    const float A  = (s > 0.0f) ? 2.0f * sqrtf(s) : 1.0f;

    // cot / A / 4  (the /4 is exact, so fold as *0.25 after the division)
    const float c0 = ((l2 * l2 + l3 * l3 - l1 * l1) / A) * 0.25f; // row i1, col i2
    const float c1 = ((l1 * l1 + l3 * l3 - l2 * l2) / A) * 0.25f; // row i2, col i0
    const float c2 = ((l1 * l1 + l2 * l2 - l3 * l3) / A) * 0.25f; // row i0, col i1

    const size_t n = (size_t)N;
    // scatter (r, c, v): off-diagonals get -v, both diagonals get +v
    {
        const int r = i1, c = i2; const float v = c0;
        atomicAdd(&L[(size_t)r * n + c], -v);
        atomicAdd(&L[(size_t)c * n + r], -v);
        atomicAdd(&L[(size_t)r * n + r],  v);
        atomicAdd(&L[(size_t)c * n + c],  v);
    }
    {
        const int r = i2, c = i0; const float v = c1;
        atomicAdd(&L[(size_t)r * n + c], -v);
        atomicAdd(&L[(size_t)c * n + r], -v);
        atomicAdd(&L[(size_t)r * n + r],  v);
        atomicAdd(&L[(size_t)c * n + c],  v);
    }
    {
        const int r = i0, c = i1; const float v = c2;
        atomicAdd(&L[(size_t)r * n + c], -v);
        atomicAdd(&L[(size_t)c * n + r], -v);
        atomicAdd(&L[(size_t)r * n + r],  v);
        atomicAdd(&L[(size_t)c * n + c],  v);
    }
}

extern "C" void kernel_launch(void* const* d_in, const int* in_sizes, int n_in,
                              void* d_out, int out_size, void* d_ws, size_t ws_size,
                              hipStream_t stream) {
    const float* V = (const float*)d_in[0];
    const int* Fw  = (const int*)d_in[1];
    float* L       = (float*)d_out;

    const int N  = in_sizes[0] / 3;   // 8192 vertices
    const int nF = in_sizes[1] / 3;   // 16384 faces

    // Zero the 256 MB output, then scatter. Same stream -> ordered.
    hipMemsetAsync(d_out, 0, (size_t)out_size * sizeof(float), stream);

    const int block = 256;
    const int grid = (nF + block - 1) / block;
    face_scatter_kernel<<<grid, block, 0, stream>>>(V, Fw, L, nF, N);
}